// Round 7
// baseline (16.975 us; speedup 1.0000x reference)
//
#include <hip/hip_runtime.h>
#include <hip/hip_bf16.h>

#define EPS 1e-12f

constexpr int B = 32, P = 1000, H = 128, D = 64;
constexpr int TIL = 63;                 // ceil(P/16) p-tiles of 16

typedef __attribute__((ext_vector_type(8))) short bf16x8;   // MFMA A/B frag
typedef __attribute__((ext_vector_type(4))) float f32x4;

__device__ __forceinline__ float fast_rcp(float x)  { return __builtin_amdgcn_rcpf(x); }
__device__ __forceinline__ float fast_sqrt(float x) { return __builtin_amdgcn_sqrtf(x); }

__device__ __forceinline__ int pk2(float x, float y) {
    union { __hip_bfloat162 t; int i; } u;
    u.t = __float22bfloat162_rn(make_float2(x, y));   // v_cvt_pk_bf16_f32
    return u.i;
}
__device__ __forceinline__ bf16x8 cvt8(f32x4 a, f32x4 b) {
    union { bf16x8 v; int i[4]; } u;
    u.i[0] = pk2(a.x, a.y); u.i[1] = pk2(a.z, a.w);
    u.i[2] = pk2(b.x, b.y); u.i[3] = pk2(b.z, b.w);
    return u.v;
}
__device__ __forceinline__ f32x4 scale4(f32x4 v, float s) {
    f32x4 r; r.x = v.x * s; r.y = v.y * s; r.z = v.z * s; r.w = v.w * s;
    return r;
}
__device__ __forceinline__ float sumsq16(f32x4 a, f32x4 b, f32x4 c, f32x4 d) {
    return (a.x*a.x + a.y*a.y + a.z*a.z + a.w*a.w)
         + (b.x*b.x + b.y*b.y + b.z*b.z + b.w*b.w)
         + (c.x*c.x + c.y*c.y + c.z*c.z + c.w*c.w)
         + (d.x*d.x + d.y*d.y + d.z*d.z + d.w*d.w);
}

// 2 waves per (b, 16-p tile): wave w owns h rows [w*64, w*64+64), depth-1 prefetch.
__global__ __launch_bounds__(128, 4)
void ex2vec_kernel(const int* __restrict__ user_index,
                   const int* __restrict__ pred_items,
                   const int* __restrict__ hist_items,
                   const float* __restrict__ hist_td,
                   const float* __restrict__ hist_w,
                   const float* __restrict__ emb_user,
                   const float* __restrict__ emb_item,
                   const float* __restrict__ user_lamb,
                   const float* __restrict__ user_bias,
                   const float* __restrict__ item_bias,
                   const float* __restrict__ sc_global_lamb,
                   const float* __restrict__ sc_alpha,
                   const float* __restrict__ sc_beta,
                   const float* __restrict__ sc_gamma,
                   const float* __restrict__ sc_cutoff,
                   const float* __restrict__ sc_smooth,
                   const float* __restrict__ sc_force,
                   float* __restrict__ out)
{
    __shared__ float red[2][16];

    const int b    = blockIdx.x / TIL;
    const int tile = blockIdx.x - b * TIL;
    const int tid  = threadIdx.x;
    const int w    = tid >> 6;          // wave: h-half owner
    const int lane = tid & 63;
    const int col  = lane & 15;         // p col / MFMA n; also A-row index for gathers
    const int kg   = lane >> 4;         // k-group: d = kg*8..+7 (+32 for k-half 1)

    const int pg   = tile * 16 + col;
    const int pgc  = pg < P ? pg : P - 1;
    const int pidx = pred_items[b * P + pgc];

    // ---- p fragments ----
    const float* prow = emb_item + (size_t)pidx * D + kg * 8;
    f32x4 p0 = *(const f32x4*)(prow);
    f32x4 p1 = *(const f32x4*)(prow + 4);
    f32x4 p2 = *(const f32x4*)(prow + 32);
    f32x4 p3 = *(const f32x4*)(prow + 36);

    // ---- this wave's 4 h-tiles of 16 ----
    int hidx[4];
    #pragma unroll
    for (int ti = 0; ti < 4; ++ti)
        hidx[ti] = hist_items[b * H + (w * 4 + ti) * 16 + col];

    float pp = sumsq16(p0, p1, p2, p3);
    pp += __shfl_xor(pp, 16);
    pp += __shfl_xor(pp, 32);

    // B frags carry -2*p (exact bf16 scaling): MFMA yields pp - 2*h.p directly
    const bf16x8 bfr0 = cvt8(scale4(p0, -2.f), scale4(p1, -2.f));
    const bf16x8 bfr1 = cvt8(scale4(p2, -2.f), scale4(p3, -2.f));

    const float cutoff = *sc_cutoff;
    const float smooth = *sc_smooth;
    const float fs     = *sc_force * smooth;

    // ---- prefetch ti=0 ----
    const float* hrp = emb_item + (size_t)hidx[0] * D + kg * 8;
    f32x4 a0 = *(const f32x4*)(hrp);
    f32x4 a1 = *(const f32x4*)(hrp + 4);
    f32x4 a2 = *(const f32x4*)(hrp + 32);
    f32x4 a3 = *(const f32x4*)(hrp + 36);

    float pres = 0.f;
    #pragma unroll
    for (int ti = 0; ti < 4; ++ti) {
        const f32x4 c0 = a0, c1 = a1, c2 = a2, c3 = a3;
        if (ti < 3) {                   // issue next gather before processing current
            const float* nx = emb_item + (size_t)hidx[ti + 1] * D + kg * 8;
            a0 = *(const f32x4*)(nx);
            a1 = *(const f32x4*)(nx + 4);
            a2 = *(const f32x4*)(nx + 32);
            a3 = *(const f32x4*)(nx + 36);
        }

        float s = sumsq16(c0, c1, c2, c3);      // hh partial, fold over kg
        s += __shfl_xor(s, 16);
        s += __shfl_xor(s, 32);
        const int r0 = b * H + (w * 4 + ti) * 16 + col;
        const float tdc = hist_w[r0] * __frsqrt_rn(hist_td[r0] + cutoff);

        const bf16x8 af0 = cvt8(c0, c1);
        const bf16x8 af1 = cvt8(c2, c3);
        f32x4 acc = {pp, pp, pp, pp};           // C-init: + ||p||^2
        acc = __builtin_amdgcn_mfma_f32_16x16x32_bf16(af0, bfr0, acc, 0, 0, 0);
        acc = __builtin_amdgcn_mfma_f32_16x16x32_bf16(af1, bfr1, acc, 0, 0, 0);

        #pragma unroll
        for (int j = 0; j < 4; ++j) {
            const int src   = (kg << 2) | j;    // lane holding row stats
            const float hhv = __shfl(s, src);
            const float tdv = __shfl(tdc, src);
            const float sq   = acc[j] + hhv;    // hh + pp - 2 h.p
            const float dist = fast_sqrt(fmaxf(sq, 0.f) + EPS);
            const float x    = smooth * fast_rcp(1.f + dist) - fs;
            pres += tdv * fast_rcp(1.f + __expf(-x));
        }
    }
    pres += __shfl_xor(pres, 16);       // fold kg partitions -> this wave's 64 h
    pres += __shfl_xor(pres, 32);
    if (lane < 16) red[w][col] = pres;

    // ---- dist_ui (f32 exact) on wave 0 while wave 1 finishes ----
    const int uidx = user_index[b];
    float dp = 0.f;
    if (w == 0) {
        const float* urow = emb_user + (size_t)uidx * D + kg * 8;
        f32x4 d0 = *(const f32x4*)(urow)      - p0;
        f32x4 d1 = *(const f32x4*)(urow + 4)  - p1;
        f32x4 d2 = *(const f32x4*)(urow + 32) - p2;
        f32x4 d3 = *(const f32x4*)(urow + 36) - p3;
        dp = sumsq16(d0, d1, d2, d3);
        dp += __shfl_xor(dp, 16);
        dp += __shfl_xor(dp, 32);
    }
    __syncthreads();

    if (w == 0 && lane < 16 && pg < P) {
        const float res       = red[0][col] + red[1][col];
        const float inv_denom = 1.f + __expf(fs - smooth);
        const float lamb      = (*sc_global_lamb + user_lamb[uidx]) * inv_denom;
        const float dist_ui   = fast_sqrt(dp + EPS);
        const float o = fmaxf(0.f, dist_ui - lamb * res);
        out[b * P + pg] = (*sc_alpha) * o + (*sc_beta) * o * o + (*sc_gamma)
                          + user_bias[uidx] + item_bias[pidx];
    }
}

extern "C" void kernel_launch(void* const* d_in, const int* in_sizes, int n_in,
                              void* d_out, int out_size, void* d_ws, size_t ws_size,
                              hipStream_t stream) {
    (void)in_sizes; (void)n_in; (void)d_ws; (void)ws_size; (void)out_size;
    ex2vec_kernel<<<dim3(B * TIL), dim3(128), 0, stream>>>(
        (const int*)d_in[0],  (const int*)d_in[1],  (const int*)d_in[2],
        (const float*)d_in[3], (const float*)d_in[4],
        (const float*)d_in[5], (const float*)d_in[6],
        (const float*)d_in[7], (const float*)d_in[8], (const float*)d_in[9],
        (const float*)d_in[10], (const float*)d_in[11], (const float*)d_in[12],
        (const float*)d_in[13], (const float*)d_in[14], (const float*)d_in[15],
        (const float*)d_in[16], (float*)d_out);
}

// Round 8
// 12.439 us; speedup vs baseline: 1.3647x; 1.3647x over previous
//
#include <hip/hip_runtime.h>
#include <hip/hip_bf16.h>

#define EPS 1e-12f

constexpr int B = 32, P = 1000, H = 128, D = 64;
constexpr int PT = 64;                  // p per block (4 waves x 16 cols)
constexpr int TILB = 16;                // blocks per b; grid = 512
constexpr int NT = 256;

typedef __attribute__((ext_vector_type(8))) short bf16x8;   // MFMA A/B frag
typedef __attribute__((ext_vector_type(4))) float f32x4;

__device__ __forceinline__ float fast_rcp(float x)  { return __builtin_amdgcn_rcpf(x); }
__device__ __forceinline__ float fast_sqrt(float x) { return __builtin_amdgcn_sqrtf(x); }

__device__ __forceinline__ int pk2(float x, float y) {
    union { __hip_bfloat162 t; int i; } u;
    u.t = __float22bfloat162_rn(make_float2(x, y));   // v_cvt_pk_bf16_f32
    return u.i;
}
__device__ __forceinline__ bf16x8 cvt8(f32x4 a, f32x4 b) {
    union { bf16x8 v; int i[4]; } u;
    u.i[0] = pk2(a.x, a.y); u.i[1] = pk2(a.z, a.w);
    u.i[2] = pk2(b.x, b.y); u.i[3] = pk2(b.z, b.w);
    return u.v;
}
__device__ __forceinline__ f32x4 scale4(f32x4 v, float s) {
    f32x4 r; r.x = v.x * s; r.y = v.y * s; r.z = v.z * s; r.w = v.w * s;
    return r;
}
__device__ __forceinline__ float sumsq16(f32x4 a, f32x4 b, f32x4 c, f32x4 d) {
    return (a.x*a.x + a.y*a.y + a.z*a.z + a.w*a.w)
         + (b.x*b.x + b.y*b.y + b.z*b.z + b.w*b.w)
         + (c.x*c.x + c.y*c.y + c.z*c.z + c.w*c.w)
         + (d.x*d.x + d.y*d.y + d.z*d.z + d.w*d.w);
}

// Block = (b, 64-p tile). Stage all 128 h rows ONCE to LDS (bf16 frags + hh/td);
// each wave runs 16 p-cols x 128 h with an LDS-only inner loop.
__global__ __launch_bounds__(NT, 4)
void ex2vec_kernel(const int* __restrict__ user_index,
                   const int* __restrict__ pred_items,
                   const int* __restrict__ hist_items,
                   const float* __restrict__ hist_td,
                   const float* __restrict__ hist_w,
                   const float* __restrict__ emb_user,
                   const float* __restrict__ emb_item,
                   const float* __restrict__ user_lamb,
                   const float* __restrict__ user_bias,
                   const float* __restrict__ item_bias,
                   const float* __restrict__ sc_global_lamb,
                   const float* __restrict__ sc_alpha,
                   const float* __restrict__ sc_beta,
                   const float* __restrict__ sc_gamma,
                   const float* __restrict__ sc_cutoff,
                   const float* __restrict__ sc_smooth,
                   const float* __restrict__ sc_force,
                   float* __restrict__ out)
{
    __shared__ bf16x8 afs[2][H][4];     // [k-half][row][kg] 16B frags = 16 KB
    __shared__ float  hh[H];            // ||h_row||^2
    __shared__ float  tds[H];           // w / sqrt(td + cutoff)

    const int b    = blockIdx.x >> 4;
    const int tile = blockIdx.x & 15;
    const int tid  = threadIdx.x;
    const int w    = tid >> 6;
    const int lane = tid & 63;
    const int col  = lane & 15;         // p col / MFMA n; A-row selector in loop
    const int kg   = lane >> 4;         // k-group: d = kg*8..+7 (+32 for k-half 1)

    const int pg   = tile * PT + w * 16 + col;
    const int pgc  = pg < P ? pg : P - 1;
    const int pidx = pred_items[b * P + pgc];

    // ---- issue p-gather first (independent of staging) ----
    const float* prow = emb_item + (size_t)pidx * D + kg * 8;
    const f32x4 p0 = *(const f32x4*)(prow);
    const f32x4 p1 = *(const f32x4*)(prow + 4);
    const f32x4 p2 = *(const f32x4*)(prow + 32);
    const f32x4 p3 = *(const f32x4*)(prow + 36);

    const float cutoff = *sc_cutoff;

    // ---- stage h: thread owns (row r, half hf) = 32 floats ----
    {
        const int r  = tid >> 1;
        const int hf = tid & 1;
        const int hidx = hist_items[b * H + r];
        const f32x4* hsrc = (const f32x4*)(emb_item + (size_t)hidx * D + hf * 32);
        const f32x4 v0 = hsrc[0], v1 = hsrc[1], v2 = hsrc[2], v3 = hsrc[3];
        const f32x4 v4 = hsrc[4], v5 = hsrc[5], v6 = hsrc[6], v7 = hsrc[7];

        float s = sumsq16(v0, v1, v2, v3) + sumsq16(v4, v5, v6, v7);
        s += __shfl_xor(s, 1);          // combine the two halves
        if (hf == 0) {
            hh[r]  = s;
            tds[r] = hist_w[b * H + r] * __frsqrt_rn(hist_td[b * H + r] + cutoff);
        }
        // k-half hf, row r, kg: floats d[hf*32 + kg*8 .. +8) = v[2kg], v[2kg+1]
        afs[hf][r][0] = cvt8(v0, v1);
        afs[hf][r][1] = cvt8(v2, v3);
        afs[hf][r][2] = cvt8(v4, v5);
        afs[hf][r][3] = cvt8(v6, v7);
    }

    // ---- pp + B frags (carry -2*p: MFMA yields pp - 2 h.p with C-init pp) ----
    float pp = sumsq16(p0, p1, p2, p3);
    pp += __shfl_xor(pp, 16);
    pp += __shfl_xor(pp, 32);
    const bf16x8 bfr0 = cvt8(scale4(p0, -2.f), scale4(p1, -2.f));
    const bf16x8 bfr1 = cvt8(scale4(p2, -2.f), scale4(p3, -2.f));

    const float smooth = *sc_smooth;
    const float fs     = *sc_force * smooth;

    __syncthreads();

    // ---- LDS-only inner loop: 8 tiles of 16 h rows ----
    float pres = 0.f;
    #pragma unroll
    for (int t = 0; t < 8; ++t) {
        const int row = t * 16 + col;
        const bf16x8 af0 = afs[0][row][kg];             // conflict-free b128
        const bf16x8 af1 = afs[1][row][kg];
        const f32x4  hh4 = *(const f32x4*)(hh  + t * 16 + kg * 4);  // broadcast
        const f32x4  td4 = *(const f32x4*)(tds + t * 16 + kg * 4);

        f32x4 acc = {pp, pp, pp, pp};
        acc = __builtin_amdgcn_mfma_f32_16x16x32_bf16(af0, bfr0, acc, 0, 0, 0);
        acc = __builtin_amdgcn_mfma_f32_16x16x32_bf16(af1, bfr1, acc, 0, 0, 0);

        #pragma unroll
        for (int j = 0; j < 4; ++j) {
            const float sq   = acc[j] + hh4[j];         // hh + pp - 2 h.p
            const float dist = fast_sqrt(fmaxf(sq, 0.f) + EPS);
            const float x    = smooth * fast_rcp(1.f + dist) - fs;
            pres += td4[j] * fast_rcp(1.f + __expf(-x));
        }
    }
    pres += __shfl_xor(pres, 16);       // fold kg partitions -> all 128 h
    pres += __shfl_xor(pres, 32);

    // ---- dist_ui (f32 exact), cooperative over kg ----
    const int uidx = user_index[b];
    const float* urow = emb_user + (size_t)uidx * D + kg * 8;
    f32x4 d0 = *(const f32x4*)(urow)      - p0;
    f32x4 d1 = *(const f32x4*)(urow + 4)  - p1;
    f32x4 d2 = *(const f32x4*)(urow + 32) - p2;
    f32x4 d3 = *(const f32x4*)(urow + 36) - p3;
    float dp = sumsq16(d0, d1, d2, d3);
    dp += __shfl_xor(dp, 16);
    dp += __shfl_xor(dp, 32);

    if (lane < 16 && pg < P) {
        const float inv_denom = 1.f + __expf(fs - smooth);
        const float lamb      = (*sc_global_lamb + user_lamb[uidx]) * inv_denom;
        const float dist_ui   = fast_sqrt(dp + EPS);
        const float o = fmaxf(0.f, dist_ui - lamb * pres);
        out[b * P + pg] = (*sc_alpha) * o + (*sc_beta) * o * o + (*sc_gamma)
                          + user_bias[uidx] + item_bias[pidx];
    }
}

extern "C" void kernel_launch(void* const* d_in, const int* in_sizes, int n_in,
                              void* d_out, int out_size, void* d_ws, size_t ws_size,
                              hipStream_t stream) {
    (void)in_sizes; (void)n_in; (void)d_ws; (void)ws_size; (void)out_size;
    ex2vec_kernel<<<dim3(B * TILB), dim3(NT), 0, stream>>>(
        (const int*)d_in[0],  (const int*)d_in[1],  (const int*)d_in[2],
        (const float*)d_in[3], (const float*)d_in[4],
        (const float*)d_in[5], (const float*)d_in[6],
        (const float*)d_in[7], (const float*)d_in[8], (const float*)d_in[9],
        (const float*)d_in[10], (const float*)d_in[11], (const float*)d_in[12],
        (const float*)d_in[13], (const float*)d_in[14], (const float*)d_in[15],
        (const float*)d_in[16], (float*)d_out);
}

// Round 9
// 11.145 us; speedup vs baseline: 1.5231x; 1.1161x over previous
//
#include <hip/hip_runtime.h>
#include <hip/hip_bf16.h>

#define EPS 1e-12f

constexpr int B = 32, P = 1000, H = 128, D = 64;
constexpr int PT = 128;                 // p per block (8 waves x 16 cols)
constexpr int TILB = 8;                 // blocks per b; grid = 256 (1 per CU)
constexpr int NT = 512;

typedef __attribute__((ext_vector_type(8))) short bf16x8;   // MFMA A/B frag
typedef __attribute__((ext_vector_type(4))) float f32x4;

__device__ __forceinline__ float fast_rcp(float x)  { return __builtin_amdgcn_rcpf(x); }
__device__ __forceinline__ float fast_sqrt(float x) { return __builtin_amdgcn_sqrtf(x); }

__device__ __forceinline__ int pk2(float x, float y) {
    union { __hip_bfloat162 t; int i; } u;
    u.t = __float22bfloat162_rn(make_float2(x, y));   // v_cvt_pk_bf16_f32
    return u.i;
}
__device__ __forceinline__ bf16x8 cvt8(f32x4 a, f32x4 b) {
    union { bf16x8 v; int i[4]; } u;
    u.i[0] = pk2(a.x, a.y); u.i[1] = pk2(a.z, a.w);
    u.i[2] = pk2(b.x, b.y); u.i[3] = pk2(b.z, b.w);
    return u.v;
}
__device__ __forceinline__ f32x4 scale4(f32x4 v, float s) {
    f32x4 r; r.x = v.x * s; r.y = v.y * s; r.z = v.z * s; r.w = v.w * s;
    return r;
}
__device__ __forceinline__ float sumsq16(f32x4 a, f32x4 b, f32x4 c, f32x4 d) {
    return (a.x*a.x + a.y*a.y + a.z*a.z + a.w*a.w)
         + (b.x*b.x + b.y*b.y + b.z*b.z + b.w*b.w)
         + (c.x*c.x + c.y*c.y + c.z*c.z + c.w*c.w)
         + (d.x*d.x + d.y*d.y + d.z*d.z + d.w*d.w);
}

// Block = (b, 128-p tile), 8 waves. Stage all 128 h rows ONCE to LDS
// (bf16 A-frags + hh/td); each wave runs 16 p-cols x 128 h LDS-only.
__global__ __launch_bounds__(NT, 2)
void ex2vec_kernel(const int* __restrict__ user_index,
                   const int* __restrict__ pred_items,
                   const int* __restrict__ hist_items,
                   const float* __restrict__ hist_td,
                   const float* __restrict__ hist_w,
                   const float* __restrict__ emb_user,
                   const float* __restrict__ emb_item,
                   const float* __restrict__ user_lamb,
                   const float* __restrict__ user_bias,
                   const float* __restrict__ item_bias,
                   const float* __restrict__ sc_global_lamb,
                   const float* __restrict__ sc_alpha,
                   const float* __restrict__ sc_beta,
                   const float* __restrict__ sc_gamma,
                   const float* __restrict__ sc_cutoff,
                   const float* __restrict__ sc_smooth,
                   const float* __restrict__ sc_force,
                   float* __restrict__ out)
{
    __shared__ bf16x8 afs[2][H][4];     // [k-half][row][kg] 16B frags = 16 KB
    __shared__ float  hh[H];            // ||h_row||^2
    __shared__ float  tds[H];           // w / sqrt(td + cutoff)

    const int b    = blockIdx.x >> 3;
    const int tile = blockIdx.x & 7;
    const int tid  = threadIdx.x;
    const int w    = tid >> 6;
    const int lane = tid & 63;
    const int col  = lane & 15;         // p col / MFMA n
    const int kg   = lane >> 4;         // k-group: d = kg*8..+7 (+32 for k-half 1)

    const int pg   = tile * PT + w * 16 + col;
    const int pgc  = pg < P ? pg : P - 1;
    const int pidx = pred_items[b * P + pgc];

    // ---- issue p-gather first (independent of staging) ----
    const float* prow = emb_item + (size_t)pidx * D + kg * 8;
    const f32x4 p0 = *(const f32x4*)(prow);
    const f32x4 p1 = *(const f32x4*)(prow + 4);
    const f32x4 p2 = *(const f32x4*)(prow + 32);
    const f32x4 p3 = *(const f32x4*)(prow + 36);

    const float cutoff = *sc_cutoff;

    // ---- stage h: thread owns (row r, quarter q) = 16 floats ----
    {
        const int r = tid >> 2;         // 0..127
        const int q = tid & 3;          // quarter: d = q*16 .. q*16+15
        const int hidx = hist_items[b * H + r];
        const f32x4* hsrc = (const f32x4*)(emb_item + (size_t)hidx * D + q * 16);
        const f32x4 v0 = hsrc[0], v1 = hsrc[1], v2 = hsrc[2], v3 = hsrc[3];

        float s = sumsq16(v0, v1, v2, v3);
        s += __shfl_xor(s, 1);          // fold the 4 quarters (lanes q in bits 0-1)
        s += __shfl_xor(s, 2);
        if (q == 0) {
            hh[r]  = s;
            tds[r] = hist_w[b * H + r] * __frsqrt_rn(hist_td[b * H + r] + cutoff);
        }
        // quarter q covers kg = 2q (floats 0-7 -> v0,v1) and 2q+1 (8-15 -> v2,v3)
        afs[q >> 1][r][(q & 1) * 2]     = cvt8(v0, v1);
        afs[q >> 1][r][(q & 1) * 2 + 1] = cvt8(v2, v3);
    }

    // ---- pp + B frags (carry -2*p: MFMA yields pp - 2 h.p with C-init pp) ----
    float pp = sumsq16(p0, p1, p2, p3);
    pp += __shfl_xor(pp, 16);
    pp += __shfl_xor(pp, 32);
    const bf16x8 bfr0 = cvt8(scale4(p0, -2.f), scale4(p1, -2.f));
    const bf16x8 bfr1 = cvt8(scale4(p2, -2.f), scale4(p3, -2.f));

    const float smooth = *sc_smooth;
    const float fs     = *sc_force * smooth;

    __syncthreads();

    // ---- LDS-only inner loop: 8 tiles of 16 h rows ----
    float pres = 0.f;
    #pragma unroll
    for (int t = 0; t < 8; ++t) {
        const int row = t * 16 + col;
        const bf16x8 af0 = afs[0][row][kg];             // conflict-free b128
        const bf16x8 af1 = afs[1][row][kg];
        const f32x4  hh4 = *(const f32x4*)(hh  + t * 16 + kg * 4);  // broadcast
        const f32x4  td4 = *(const f32x4*)(tds + t * 16 + kg * 4);

        f32x4 acc = {pp, pp, pp, pp};
        acc = __builtin_amdgcn_mfma_f32_16x16x32_bf16(af0, bfr0, acc, 0, 0, 0);
        acc = __builtin_amdgcn_mfma_f32_16x16x32_bf16(af1, bfr1, acc, 0, 0, 0);

        #pragma unroll
        for (int j = 0; j < 4; ++j) {
            const float sq   = acc[j] + hh4[j];         // hh + pp - 2 h.p
            const float dist = fast_sqrt(fmaxf(sq, 0.f) + EPS);
            const float x    = smooth * fast_rcp(1.f + dist) - fs;
            pres += td4[j] * fast_rcp(1.f + __expf(-x));
        }
    }
    pres += __shfl_xor(pres, 16);       // fold kg partitions -> all 128 h
    pres += __shfl_xor(pres, 32);

    // ---- dist_ui (f32 exact), cooperative over kg ----
    const int uidx = user_index[b];
    const float* urow = emb_user + (size_t)uidx * D + kg * 8;
    f32x4 d0 = *(const f32x4*)(urow)      - p0;
    f32x4 d1 = *(const f32x4*)(urow + 4)  - p1;
    f32x4 d2 = *(const f32x4*)(urow + 32) - p2;
    f32x4 d3 = *(const f32x4*)(urow + 36) - p3;
    float dp = sumsq16(d0, d1, d2, d3);
    dp += __shfl_xor(dp, 16);
    dp += __shfl_xor(dp, 32);

    if (lane < 16 && pg < P) {
        const float inv_denom = 1.f + __expf(fs - smooth);
        const float lamb      = (*sc_global_lamb + user_lamb[uidx]) * inv_denom;
        const float dist_ui   = fast_sqrt(dp + EPS);
        const float o = fmaxf(0.f, dist_ui - lamb * pres);
        out[b * P + pg] = (*sc_alpha) * o + (*sc_beta) * o * o + (*sc_gamma)
                          + user_bias[uidx] + item_bias[pidx];
    }
}

extern "C" void kernel_launch(void* const* d_in, const int* in_sizes, int n_in,
                              void* d_out, int out_size, void* d_ws, size_t ws_size,
                              hipStream_t stream) {
    (void)in_sizes; (void)n_in; (void)d_ws; (void)ws_size; (void)out_size;
    ex2vec_kernel<<<dim3(B * TILB), dim3(NT), 0, stream>>>(
        (const int*)d_in[0],  (const int*)d_in[1],  (const int*)d_in[2],
        (const float*)d_in[3], (const float*)d_in[4],
        (const float*)d_in[5], (const float*)d_in[6],
        (const float*)d_in[7], (const float*)d_in[8], (const float*)d_in[9],
        (const float*)d_in[10], (const float*)d_in[11], (const float*)d_in[12],
        (const float*)d_in[13], (const float*)d_in[14], (const float*)d_in[15],
        (const float*)d_in[16], (float*)d_out);
}

// Round 10
// 11.063 us; speedup vs baseline: 1.5345x; 1.0074x over previous
//
#include <hip/hip_runtime.h>
#include <hip/hip_bf16.h>

#define EPS 1e-12f

constexpr int B = 32, P = 1000, H = 128, D = 64;
constexpr int PT = 128;                 // p per block (8 waves x 16 cols)
constexpr int TILB = 8;                 // blocks per b; grid = 256 (1 per CU)
constexpr int NT = 512;

typedef __attribute__((ext_vector_type(8))) short bf16x8;   // MFMA A/B frag
typedef __attribute__((ext_vector_type(4))) float f32x4;

__device__ __forceinline__ float fast_rcp(float x)  { return __builtin_amdgcn_rcpf(x); }
__device__ __forceinline__ float fast_sqrt(float x) { return __builtin_amdgcn_sqrtf(x); }

__device__ __forceinline__ int pk2(float x, float y) {
    union { __hip_bfloat162 t; int i; } u;
    u.t = __float22bfloat162_rn(make_float2(x, y));   // v_cvt_pk_bf16_f32
    return u.i;
}
__device__ __forceinline__ bf16x8 cvt8(f32x4 a, f32x4 b) {
    union { bf16x8 v; int i[4]; } u;
    u.i[0] = pk2(a.x, a.y); u.i[1] = pk2(a.z, a.w);
    u.i[2] = pk2(b.x, b.y); u.i[3] = pk2(b.z, b.w);
    return u.v;
}
__device__ __forceinline__ f32x4 scale4(f32x4 v, float s) {
    f32x4 r; r.x = v.x * s; r.y = v.y * s; r.z = v.z * s; r.w = v.w * s;
    return r;
}
__device__ __forceinline__ float sumsq16(f32x4 a, f32x4 b, f32x4 c, f32x4 d) {
    return (a.x*a.x + a.y*a.y + a.z*a.z + a.w*a.w)
         + (b.x*b.x + b.y*b.y + b.z*b.z + b.w*b.w)
         + (c.x*c.x + c.y*c.y + c.z*c.z + c.w*c.w)
         + (d.x*d.x + d.y*d.y + d.z*d.z + d.w*d.w);
}

// Bank-conflict swizzle: frag unit stride per row is 64B, which aliases the
// 128B bank cycle 2:1 (8-way conflict). XOR kg with row bits 1-2 -> rows 0-7
// cover all 32 banks; residual 2-way aliasing is free (m136).
__device__ __forceinline__ int swz(int row, int kg) { return kg ^ ((row >> 1) & 3); }

// Block = (b, 128-p tile), 8 waves. Stage all 128 h rows ONCE to LDS
// (bf16 A-frags + hh/td); each wave runs 16 p-cols x 128 h LDS-only.
__global__ __launch_bounds__(NT, 2)
void ex2vec_kernel(const int* __restrict__ user_index,
                   const int* __restrict__ pred_items,
                   const int* __restrict__ hist_items,
                   const float* __restrict__ hist_td,
                   const float* __restrict__ hist_w,
                   const float* __restrict__ emb_user,
                   const float* __restrict__ emb_item,
                   const float* __restrict__ user_lamb,
                   const float* __restrict__ user_bias,
                   const float* __restrict__ item_bias,
                   const float* __restrict__ sc_global_lamb,
                   const float* __restrict__ sc_alpha,
                   const float* __restrict__ sc_beta,
                   const float* __restrict__ sc_gamma,
                   const float* __restrict__ sc_cutoff,
                   const float* __restrict__ sc_smooth,
                   const float* __restrict__ sc_force,
                   float* __restrict__ out)
{
    __shared__ bf16x8 afs[2][H][4];     // [k-half][row][kg-swizzled] = 16 KB
    __shared__ float  hh[H];            // ||h_row||^2
    __shared__ float  tds[H];           // w / sqrt(td + cutoff)

    const int b    = blockIdx.x >> 3;
    const int tile = blockIdx.x & 7;
    const int tid  = threadIdx.x;
    const int w    = tid >> 6;
    const int lane = tid & 63;
    const int col  = lane & 15;         // p col / MFMA n
    const int kg   = lane >> 4;         // k-group: d = kg*8..+7 (+32 for k-half 1)

    const int pg   = tile * PT + w * 16 + col;
    const int pgc  = pg < P ? pg : P - 1;
    const int pidx = pred_items[b * P + pgc];

    // ---- issue p-gather first (independent of staging) ----
    const float* prow = emb_item + (size_t)pidx * D + kg * 8;
    const f32x4 p0 = *(const f32x4*)(prow);
    const f32x4 p1 = *(const f32x4*)(prow + 4);
    const f32x4 p2 = *(const f32x4*)(prow + 32);
    const f32x4 p3 = *(const f32x4*)(prow + 36);

    const float cutoff = *sc_cutoff;

    // ---- stage h: thread owns (row r, quarter q) = 16 floats ----
    {
        const int r = tid >> 2;         // 0..127
        const int q = tid & 3;          // quarter: d = q*16 .. q*16+15
        const int hidx = hist_items[b * H + r];
        const f32x4* hsrc = (const f32x4*)(emb_item + (size_t)hidx * D + q * 16);
        const f32x4 v0 = hsrc[0], v1 = hsrc[1], v2 = hsrc[2], v3 = hsrc[3];

        float s = sumsq16(v0, v1, v2, v3);
        s += __shfl_xor(s, 1);          // fold the 4 quarters (lanes q in bits 0-1)
        s += __shfl_xor(s, 2);
        if (q == 0) {
            hh[r]  = s;
            tds[r] = hist_w[b * H + r] * __frsqrt_rn(hist_td[b * H + r] + cutoff);
        }
        // quarter q covers kg = 2q (floats 0-7 -> v0,v1) and 2q+1 (8-15 -> v2,v3)
        afs[q >> 1][r][swz(r, (q & 1) * 2)]     = cvt8(v0, v1);
        afs[q >> 1][r][swz(r, (q & 1) * 2 + 1)] = cvt8(v2, v3);
    }

    // ---- pp + B frags (carry -2*p: MFMA yields pp - 2 h.p with C-init pp+hh) ----
    float pp = sumsq16(p0, p1, p2, p3);
    pp += __shfl_xor(pp, 16);
    pp += __shfl_xor(pp, 32);
    const bf16x8 bfr0 = cvt8(scale4(p0, -2.f), scale4(p1, -2.f));
    const bf16x8 bfr1 = cvt8(scale4(p2, -2.f), scale4(p3, -2.f));

    const float smooth = *sc_smooth;
    const float fs     = *sc_force * smooth;

    __syncthreads();

    // ---- LDS-only inner loop: 8 tiles of 16 h rows ----
    float pres = 0.f;
    #pragma unroll
    for (int t = 0; t < 8; ++t) {
        const int row = t * 16 + col;
        const bf16x8 af0 = afs[0][row][swz(row, kg)];   // swizzled: ~conflict-free
        const bf16x8 af1 = afs[1][row][swz(row, kg)];
        const f32x4  hh4 = *(const f32x4*)(hh  + t * 16 + kg * 4);  // broadcast
        const f32x4  td4 = *(const f32x4*)(tds + t * 16 + kg * 4);

        f32x4 acc;                      // C-init: hh + pp (sq falls out of MFMA)
        acc.x = pp + hh4[0]; acc.y = pp + hh4[1];
        acc.z = pp + hh4[2]; acc.w = pp + hh4[3];
        acc = __builtin_amdgcn_mfma_f32_16x16x32_bf16(af0, bfr0, acc, 0, 0, 0);
        acc = __builtin_amdgcn_mfma_f32_16x16x32_bf16(af1, bfr1, acc, 0, 0, 0);

        #pragma unroll
        for (int j = 0; j < 4; ++j) {
            const float dist = fast_sqrt(fmaxf(acc[j], 0.f) + EPS);
            const float x    = smooth * fast_rcp(1.f + dist) - fs;
            pres += td4[j] * fast_rcp(1.f + __expf(-x));
        }
    }
    pres += __shfl_xor(pres, 16);       // fold kg partitions -> all 128 h
    pres += __shfl_xor(pres, 32);

    // ---- dist_ui (f32 exact), cooperative over kg ----
    const int uidx = user_index[b];
    const float* urow = emb_user + (size_t)uidx * D + kg * 8;
    f32x4 d0 = *(const f32x4*)(urow)      - p0;
    f32x4 d1 = *(const f32x4*)(urow + 4)  - p1;
    f32x4 d2 = *(const f32x4*)(urow + 32) - p2;
    f32x4 d3 = *(const f32x4*)(urow + 36) - p3;
    float dp = sumsq16(d0, d1, d2, d3);
    dp += __shfl_xor(dp, 16);
    dp += __shfl_xor(dp, 32);

    if (lane < 16 && pg < P) {
        const float inv_denom = 1.f + __expf(fs - smooth);
        const float lamb      = (*sc_global_lamb + user_lamb[uidx]) * inv_denom;
        const float dist_ui   = fast_sqrt(dp + EPS);
        const float o = fmaxf(0.f, dist_ui - lamb * pres);
        out[b * P + pg] = (*sc_alpha) * o + (*sc_beta) * o * o + (*sc_gamma)
                          + user_bias[uidx] + item_bias[pidx];
    }
}

extern "C" void kernel_launch(void* const* d_in, const int* in_sizes, int n_in,
                              void* d_out, int out_size, void* d_ws, size_t ws_size,
                              hipStream_t stream) {
    (void)in_sizes; (void)n_in; (void)d_ws; (void)ws_size; (void)out_size;
    ex2vec_kernel<<<dim3(B * TILB), dim3(NT), 0, stream>>>(
        (const int*)d_in[0],  (const int*)d_in[1],  (const int*)d_in[2],
        (const float*)d_in[3], (const float*)d_in[4],
        (const float*)d_in[5], (const float*)d_in[6],
        (const float*)d_in[7], (const float*)d_in[8], (const float*)d_in[9],
        (const float*)d_in[10], (const float*)d_in[11], (const float*)d_in[12],
        (const float*)d_in[13], (const float*)d_in[14], (const float*)d_in[15],
        (const float*)d_in[16], (float*)d_out);
}

// Round 11
// 10.833 us; speedup vs baseline: 1.5671x; 1.0212x over previous
//
#include <hip/hip_runtime.h>
#include <hip/hip_bf16.h>

#define EPS 1e-12f

constexpr int B = 32, P = 1000, H = 128, D = 64;
constexpr int PT = 128;                 // p per block (8 waves x 16 cols)
constexpr int NT = 512;

typedef __attribute__((ext_vector_type(8))) short bf16x8;   // MFMA A/B frag
typedef __attribute__((ext_vector_type(4))) float f32x4;

__device__ __forceinline__ float fast_rcp(float x)  { return __builtin_amdgcn_rcpf(x); }
__device__ __forceinline__ float fast_sqrt(float x) { return __builtin_amdgcn_sqrtf(x); }

__device__ __forceinline__ int pk2(float x, float y) {
    union { __hip_bfloat162 t; int i; } u;
    u.t = __float22bfloat162_rn(make_float2(x, y));   // v_cvt_pk_bf16_f32
    return u.i;
}
__device__ __forceinline__ bf16x8 cvt8(f32x4 a, f32x4 b) {
    union { bf16x8 v; int i[4]; } u;
    u.i[0] = pk2(a.x, a.y); u.i[1] = pk2(a.z, a.w);
    u.i[2] = pk2(b.x, b.y); u.i[3] = pk2(b.z, b.w);
    return u.v;
}
__device__ __forceinline__ f32x4 scale4(f32x4 v, float s) {
    f32x4 r; r.x = v.x * s; r.y = v.y * s; r.z = v.z * s; r.w = v.w * s;
    return r;
}
__device__ __forceinline__ float sumsq8(f32x4 a, f32x4 b) {
    return (a.x*a.x + a.y*a.y + a.z*a.z + a.w*a.w)
         + (b.x*b.x + b.y*b.y + b.z*b.z + b.w*b.w);
}
__device__ __forceinline__ float sumsq16(f32x4 a, f32x4 b, f32x4 c, f32x4 d) {
    return sumsq8(a, b) + sumsq8(c, d);
}

// Bank swizzle (kept from r10, free): row stride 64B aliases the 128B bank
// cycle; XOR kg with row bits 1-2.
__device__ __forceinline__ int swz(int row, int kg) { return kg ^ ((row >> 1) & 3); }

// Block j: b = j&31, tile = j>>5  ->  XCD(j) = j%8 = b%8: all 8 tiles of one b
// co-located on one XCD (32 blocks = its 32 CUs) so h-rows hit L2 after the
// first fetch instead of 8x L3 scatter. Split h-staging (T14): stage rows
// 0-63, issue 64-127 loads, barrier, compute t=0..3 (hides load latency),
// write rows 64-127, barrier, compute t=4..7.
__global__ __launch_bounds__(NT, 2)
void ex2vec_kernel(const int* __restrict__ user_index,
                   const int* __restrict__ pred_items,
                   const int* __restrict__ hist_items,
                   const float* __restrict__ hist_td,
                   const float* __restrict__ hist_w,
                   const float* __restrict__ emb_user,
                   const float* __restrict__ emb_item,
                   const float* __restrict__ user_lamb,
                   const float* __restrict__ user_bias,
                   const float* __restrict__ item_bias,
                   const float* __restrict__ sc_global_lamb,
                   const float* __restrict__ sc_alpha,
                   const float* __restrict__ sc_beta,
                   const float* __restrict__ sc_gamma,
                   const float* __restrict__ sc_cutoff,
                   const float* __restrict__ sc_smooth,
                   const float* __restrict__ sc_force,
                   float* __restrict__ out)
{
    __shared__ bf16x8 afs[2][H][4];     // [k-half][row][kg-swizzled] = 16 KB
    __shared__ float  hh[H];            // ||h_row||^2
    __shared__ float  tds[H];           // w / sqrt(td + cutoff)

    const int b    = blockIdx.x & 31;   // XCD co-location mapping
    const int tile = blockIdx.x >> 5;
    const int tid  = threadIdx.x;
    const int w    = tid >> 6;
    const int lane = tid & 63;
    const int col  = lane & 15;         // p col / MFMA n
    const int kg   = lane >> 4;         // k-group: d = kg*8..+7 (+32 for k-half 1)

    const int pg   = tile * PT + w * 16 + col;
    const int pgc  = pg < P ? pg : P - 1;
    const int pidx = pred_items[b * P + pgc];

    // ---- p-gather (independent, issue first) ----
    const float* prow = emb_item + (size_t)pidx * D + kg * 8;
    const f32x4 p0 = *(const f32x4*)(prow);
    const f32x4 p1 = *(const f32x4*)(prow + 4);
    const f32x4 p2 = *(const f32x4*)(prow + 32);
    const f32x4 p3 = *(const f32x4*)(prow + 36);

    const float cutoff = *sc_cutoff;

    // ---- staging ownership: thread = (row r8, eighth e) -> 8 floats ----
    const int r8 = tid >> 3;            // 0..63
    const int e  = tid & 7;             // floats d = e*8 .. e*8+7
    const int rA = r8;                  // phase A rows 0-63
    const int rB = 64 + r8;             // phase B rows 64-127

    // ---- stage A (rows 0-63) ----
    {
        const int hidx = hist_items[b * H + rA];
        const f32x4* src = (const f32x4*)(emb_item + (size_t)hidx * D + e * 8);
        const f32x4 v0 = src[0], v1 = src[1];
        float s = sumsq8(v0, v1);
        s += __shfl_xor(s, 1); s += __shfl_xor(s, 2); s += __shfl_xor(s, 4);
        if (e == 0) {
            hh[rA]  = s;
            tds[rA] = hist_w[b * H + rA] * __frsqrt_rn(hist_td[b * H + rA] + cutoff);
        }
        afs[e >> 2][rA][swz(rA, e & 3)] = cvt8(v0, v1);
    }

    // ---- issue B loads (rows 64-127) into registers; written after compute A ----
    const int hidxB = hist_items[b * H + rB];
    const f32x4* srcB = (const f32x4*)(emb_item + (size_t)hidxB * D + e * 8);
    const f32x4 b0 = srcB[0], b1 = srcB[1];
    const float wB = hist_w[b * H + rB];
    const float tB = hist_td[b * H + rB];

    // ---- pp + B-operand frags (carry -2*p; C-init pp+hh makes sq fall out) ----
    float pp = sumsq16(p0, p1, p2, p3);
    pp += __shfl_xor(pp, 16);
    pp += __shfl_xor(pp, 32);
    const bf16x8 bfr0 = cvt8(scale4(p0, -2.f), scale4(p1, -2.f));
    const bf16x8 bfr1 = cvt8(scale4(p2, -2.f), scale4(p3, -2.f));

    // ---- dist_ui (f32 exact) while staging loads drain ----
    const int uidx = user_index[b];
    const float* urow = emb_user + (size_t)uidx * D + kg * 8;
    f32x4 d0 = *(const f32x4*)(urow)      - p0;
    f32x4 d1 = *(const f32x4*)(urow + 4)  - p1;
    f32x4 d2 = *(const f32x4*)(urow + 32) - p2;
    f32x4 d3 = *(const f32x4*)(urow + 36) - p3;
    float dp = sumsq16(d0, d1, d2, d3);
    dp += __shfl_xor(dp, 16);
    dp += __shfl_xor(dp, 32);

    const float smooth = *sc_smooth;
    const float fs     = *sc_force * smooth;

    __syncthreads();                    // A staged

    float pres = 0.f;
    #pragma unroll
    for (int t = 0; t < 4; ++t) {       // compute A (rows 0-63); B loads in flight
        const int row = t * 16 + col;
        const bf16x8 af0 = afs[0][row][swz(row, kg)];
        const bf16x8 af1 = afs[1][row][swz(row, kg)];
        const f32x4  hh4 = *(const f32x4*)(hh  + t * 16 + kg * 4);
        const f32x4  td4 = *(const f32x4*)(tds + t * 16 + kg * 4);

        f32x4 acc;
        acc.x = pp + hh4[0]; acc.y = pp + hh4[1];
        acc.z = pp + hh4[2]; acc.w = pp + hh4[3];
        acc = __builtin_amdgcn_mfma_f32_16x16x32_bf16(af0, bfr0, acc, 0, 0, 0);
        acc = __builtin_amdgcn_mfma_f32_16x16x32_bf16(af1, bfr1, acc, 0, 0, 0);

        #pragma unroll
        for (int j = 0; j < 4; ++j) {
            const float dist = fast_sqrt(fmaxf(acc[j], 0.f) + EPS);
            const float x    = smooth * fast_rcp(1.f + dist) - fs;
            pres += td4[j] * fast_rcp(1.f + __expf(-x));
        }
    }

    // ---- write B (rows 64-127; disjoint from A reads) ----
    {
        float s = sumsq8(b0, b1);
        s += __shfl_xor(s, 1); s += __shfl_xor(s, 2); s += __shfl_xor(s, 4);
        if (e == 0) {
            hh[rB]  = s;
            tds[rB] = wB * __frsqrt_rn(tB + cutoff);
        }
        afs[e >> 2][rB][swz(rB, e & 3)] = cvt8(b0, b1);
    }
    __syncthreads();                    // B staged

    #pragma unroll
    for (int t = 4; t < 8; ++t) {       // compute B (rows 64-127)
        const int row = t * 16 + col;
        const bf16x8 af0 = afs[0][row][swz(row, kg)];
        const bf16x8 af1 = afs[1][row][swz(row, kg)];
        const f32x4  hh4 = *(const f32x4*)(hh  + t * 16 + kg * 4);
        const f32x4  td4 = *(const f32x4*)(tds + t * 16 + kg * 4);

        f32x4 acc;
        acc.x = pp + hh4[0]; acc.y = pp + hh4[1];
        acc.z = pp + hh4[2]; acc.w = pp + hh4[3];
        acc = __builtin_amdgcn_mfma_f32_16x16x32_bf16(af0, bfr0, acc, 0, 0, 0);
        acc = __builtin_amdgcn_mfma_f32_16x16x32_bf16(af1, bfr1, acc, 0, 0, 0);

        #pragma unroll
        for (int j = 0; j < 4; ++j) {
            const float dist = fast_sqrt(fmaxf(acc[j], 0.f) + EPS);
            const float x    = smooth * fast_rcp(1.f + dist) - fs;
            pres += td4[j] * fast_rcp(1.f + __expf(-x));
        }
    }
    pres += __shfl_xor(pres, 16);       // fold kg partitions -> all 128 h
    pres += __shfl_xor(pres, 32);

    if (lane < 16 && pg < P) {
        const float inv_denom = 1.f + __expf(fs - smooth);
        const float lamb      = (*sc_global_lamb + user_lamb[uidx]) * inv_denom;
        const float dist_ui   = fast_sqrt(dp + EPS);
        const float o = fmaxf(0.f, dist_ui - lamb * pres);
        out[b * P + pg] = (*sc_alpha) * o + (*sc_beta) * o * o + (*sc_gamma)
                          + user_bias[uidx] + item_bias[pidx];
    }
}

extern "C" void kernel_launch(void* const* d_in, const int* in_sizes, int n_in,
                              void* d_out, int out_size, void* d_ws, size_t ws_size,
                              hipStream_t stream) {
    (void)in_sizes; (void)n_in; (void)d_ws; (void)ws_size; (void)out_size;
    ex2vec_kernel<<<dim3(B * 8), dim3(NT), 0, stream>>>(
        (const int*)d_in[0],  (const int*)d_in[1],  (const int*)d_in[2],
        (const float*)d_in[3], (const float*)d_in[4],
        (const float*)d_in[5], (const float*)d_in[6],
        (const float*)d_in[7], (const float*)d_in[8], (const float*)d_in[9],
        (const float*)d_in[10], (const float*)d_in[11], (const float*)d_in[12],
        (const float*)d_in[13], (const float*)d_in[14], (const float*)d_in[15],
        (const float*)d_in[16], (float*)d_out);
}